// Round 14
// baseline (874.636 us; speedup 1.0000x reference)
//
#include <hip/hip_runtime.h>
#include <math.h>

#define N_STEPS 50
#define DT 0.02f

typedef __attribute__((ext_vector_type(8))) short    bf16x8;
typedef __attribute__((ext_vector_type(4))) float    f32x4;
typedef __attribute__((ext_vector_type(4))) unsigned u32x4;

// RNE float->bf16 (software, setup-time only)
__device__ inline unsigned f2bf(float f) {
    unsigned u = __builtin_bit_cast(unsigned, f);
    return ((u + 0x7FFFu + ((u >> 16) & 1u)) >> 16);
}
__device__ inline unsigned pk2(float lo, float hi) {
    return (f2bf(lo) & 0xFFFFu) | (f2bf(hi) << 16);
}
// fast per-step packed convert (1 instr)
__device__ inline unsigned cvtpk(float lo, float hi) {
    unsigned r;
    asm("v_cvt_pk_bf16_f32 %0, %1, %2" : "=v"(r) : "v"(lo), "v"(hi));
    return r;
}
__device__ inline bf16x8 mk8(unsigned a, unsigned b, unsigned cc, unsigned d) {
    u32x4 t; t.x = a; t.y = b; t.z = cc; t.w = d;
    return __builtin_bit_cast(bf16x8, t);
}
// tanh(x) = 1 - 2/(2^(x*2*log2 e) + 1); v_exp_f32 + v_rcp_f32.
__device__ inline float fast_tanh(float x) {
    float e, r;
    asm("v_exp_f32 %0, %1" : "=v"(e) : "v"(x * 2.8853900817779268f));
    asm("v_rcp_f32 %0, %1" : "=v"(r) : "v"(e + 1.0f));
    return fmaf(-2.0f, r, 1.0f);
}

// Transpose-reduce over the 2 path-tiles: lane(c,g) ends with
// sum_g pv[g&1], bitwise identical to round-11's red4 pick
// (fp add is commutative; tree shape unchanged).
__device__ inline float red2(const float pv[2], int gp) {
    float x = gp ? pv[1] : pv[0];
    float o = gp ? pv[0] : pv[1];
    x += __shfl_xor(o, 16, 64);
    x += __shfl_xor(x, 32, 64);
    return x;
}

// Block = 64 threads = ONE wave, BOTH nets, 32 paths (2 MFMA path-tiles).
//
// Round-14 change vs round 11 (the 400 us champion): occupancy was
// GRID-limited at 2 waves/SIMD (2048 waves / 1024 SIMDs) with ~25%
// issue-idle; VGPR=128 allows 4 waves/SIMD. Halve the block: 32 paths
// per wave -> 4096 waves -> 4 waves/SIMD. Lane(c,g) owns path
// 32*blk + 16*(g&1) + c; lane-groups 2,3 duplicate groups 0,1's SDE
// bitwise (redundant integration, rounds 0-5 pattern). Costs ~6% more
// VALU (SDE/dW x2 per path); buys 2x TLP against the idle.
// Also: red4 -> red2 transpose-reduce (2 shfl + 1 select per output
// vs 8 shfl + 3 selects), bitwise identical by fp-add commutativity.
// Per-path MLP arithmetic unchanged -> absmax stays 0.001953125.
// Round-13 lesson kept: NO MFMA stage 3 (LDS round-trip not worth it).
__global__ __launch_bounds__(64, 4) void bsde_kernel(
    const float* __restrict__ y0v, const float* __restrict__ Y0v,
    const float* __restrict__ qW1, const float* __restrict__ qb1,
    const float* __restrict__ qW2, const float* __restrict__ qb2,
    const float* __restrict__ qW3, const float* __restrict__ qb3,
    const float* __restrict__ zW1, const float* __restrict__ zb1,
    const float* __restrict__ zW2, const float* __restrict__ zb2,
    const float* __restrict__ zW3, const float* __restrict__ zb3,
    const float* __restrict__ dW,
    float* __restrict__ out, int B)
{
    const int lane = threadIdx.x;             // 0..63
    const int c    = lane & 15;               // path-col within a 16-tile
    const int g    = lane >> 4;               // lane group
    const int gp   = g & 1;                   // path-tile this lane integrates
    const int p    = blockIdx.x * 32 + 16 * gp + c;

    __shared__ unsigned short ex[32 * 128];   // 8KB: [path][net*64 + h1] bf16
    __shared__ __align__(16) float w3c[4][64]; // comp-major W3: 0..2 = z, 3 = q

    // ---------------- one-time W3 -> LDS table ----------------
    w3c[0][lane] = zW3[3 * lane + 0];
    w3c[1][lane] = zW3[3 * lane + 1];
    w3c[2][lane] = zW3[3 * lane + 2];
    w3c[3][lane] = qW3[lane];

    // ---------------- one-time weight fragment preload ----------------
    // mt 0..3 = z-net, mt 4..7 = q-net; h = 16*(mt&3)+c within the net.
    bf16x8 w1f[8];
#pragma unroll
    for (int mt = 0; mt < 8; ++mt) {
        const float* W1 = (mt < 4) ? zW1 : qW1;
        const float* b1 = (mt < 4) ? zb1 : qb1;
        const int h = 16 * (mt & 3) + c;
        unsigned d0 = 0, d1 = 0, d2 = 0;
        if (g == 0) {
            d0 = pk2(W1[0 * 64 + h], W1[1 * 64 + h]);   // k0=t, k1=y0
            d1 = pk2(W1[2 * 64 + h], W1[3 * 64 + h]);   // k2=y1, k3=y2
            d2 = f2bf(b1[h]) & 0xFFFFu;                 // k4=1-const row
        }
        w1f[mt] = mk8(d0, d1, d2, 0);
    }

    bf16x8 w2f[8][2];
#pragma unroll
    for (int mt = 0; mt < 8; ++mt) {
        const float* W2 = (mt < 4) ? zW2 : qW2;
        const int h = 16 * (mt & 3) + c;
#pragma unroll
        for (int kt = 0; kt < 2; ++kt) {
            const int k0 = 32 * kt + 8 * g;
            w2f[mt][kt] = mk8(
                pk2(W2[(k0 + 0) * 64 + h], W2[(k0 + 1) * 64 + h]),
                pk2(W2[(k0 + 2) * 64 + h], W2[(k0 + 3) * 64 + h]),
                pk2(W2[(k0 + 4) * 64 + h], W2[(k0 + 5) * 64 + h]),
                pk2(W2[(k0 + 6) * 64 + h], W2[(k0 + 7) * 64 + h]));
        }
    }

    f32x4 b2v[8];
#pragma unroll
    for (int mt = 0; mt < 8; ++mt) {
        const float* b2 = (mt < 4) ? zb2 : qb2;
#pragma unroll
        for (int r = 0; r < 4; ++r)
            b2v[mt][r] = b2[16 * (mt & 3) + 4 * g + r];
    }

    const float zb3_0 = zb3[0], zb3_1 = zb3[1], zb3_2 = zb3[2];
    const float qb3_0 = qb3[0];

    __syncthreads();                          // single wave; near-free

    char* exn = (char*)ex;
    const int sw = (c & 7) << 4;              // LDS XOR swizzle key (bits 4-6)
    const unsigned jp2c = (g == 0) ? 0x3F80u : 0u;   // bf16(1.0) in k=4 slot

    const float sqrt_dt = sqrtf(DT);
    float y0 = y0v[0], y1 = y0v[1], y2 = y0v[2];
    float Y  = Y0v[0];

    for (int n = 0; n < N_STEPS; ++n) {
        const float t = (float)n * DT;

        const size_t idx = ((size_t)n * (size_t)B + (size_t)p) * 3;
        const float dr0 = dW[idx + 0];
        const float dr1 = dW[idx + 1];
        const float dr2 = dW[idx + 2];

        // ---- L1: shared xf per t4, 8 MFMA (both nets), relu+pack+write ----
#pragma unroll
        for (int t4 = 0; t4 < 2; ++t4) {
            const int src = 16 * t4 + c;      // lane holding tile-t4 path c
            const float s0 = __shfl(y0, src, 64);
            const float s1 = __shfl(y1, src, 64);
            const float s2 = __shfl(y2, src, 64);
            const unsigned a = cvtpk(t,  s0);
            const unsigned b = cvtpk(s1, s2);
            const bf16x8 xf = mk8((g == 0) ? a : 0u, (g == 0) ? b : 0u, jp2c, 0u);
#pragma unroll
            for (int mt = 0; mt < 8; ++mt) {
                f32x4 c1 = __builtin_amdgcn_mfma_f32_16x16x32_bf16(
                    w1f[mt], xf, (f32x4){0.f, 0.f, 0.f, 0.f}, 0, 0, 0);
                const unsigned lo = cvtpk(fmaxf(c1[0], 0.f), fmaxf(c1[1], 0.f));
                const unsigned hi = cvtpk(fmaxf(c1[2], 0.f), fmaxf(c1[3], 0.f));
                const int off = (((16 * t4 + c) * 256) + (mt >> 2) * 128
                                 + 32 * (mt & 3) + 8 * g) ^ sw;
                *(unsigned long long*)(exn + off) =
                    ((unsigned long long)hi << 32) | (unsigned long long)lo;
            }
        }

        // ---- L2 + L3 partials, mt-outer (w3 reads hoisted per mt) ----
        float pz0[2] = {0.f, 0.f};
        float pz1[2] = {0.f, 0.f};
        float pz2[2] = {0.f, 0.f};
        float pq [2] = {0.f, 0.f};
#pragma unroll
        for (int mt = 0; mt < 8; ++mt) {
            const int hb = 16 * (mt & 3) + 4 * g;
            f32x4 wz0, wz1, wz2, wq;
            if (mt < 4) {
                wz0 = *(const f32x4*)&w3c[0][hb];
                wz1 = *(const f32x4*)&w3c[1][hb];
                wz2 = *(const f32x4*)&w3c[2][hb];
            } else {
                wq  = *(const f32x4*)&w3c[3][hb];
            }
#pragma unroll
            for (int t4 = 0; t4 < 2; ++t4) {
                const int rb = ((16 * t4 + c) * 256) + (mt >> 2) * 128 + 16 * g;
                const bf16x8 hf0 = *(const bf16x8*)(exn + ((rb +  0) ^ sw));
                const bf16x8 hf1 = *(const bf16x8*)(exn + ((rb + 64) ^ sw));
                f32x4 acc = __builtin_amdgcn_mfma_f32_16x16x32_bf16(
                    w2f[mt][0], hf0, b2v[mt], 0, 0, 0);
                acc = __builtin_amdgcn_mfma_f32_16x16x32_bf16(
                    w2f[mt][1], hf1, acc, 0, 0, 0);
#pragma unroll
                for (int r = 0; r < 4; ++r) {
                    const float h = fmaxf(acc[r], 0.f);
                    if (mt < 4) {
                        pz0[t4] = fmaf(h, wz0[r], pz0[t4]);
                        pz1[t4] = fmaf(h, wz1[r], pz1[t4]);
                        pz2[t4] = fmaf(h, wz2[r], pz2[t4]);
                    } else {
                        pq[t4]  = fmaf(h, wq[r],  pq[t4]);
                    }
                }
            }
        }

        // ---- transpose-reduce: every lane gets its own path's outputs ----
        const float oz0 = red2(pz0, gp) + zb3_0;
        const float oz1 = red2(pz1, gp) + zb3_1;
        const float oz2 = red2(pz2, gp) + zb3_2;
        const float qq  = red2(pq,  gp) + qb3_0;

        // ---- SDE update (same expression order as rounds 0-13) ----
        const float dw0 = dr0 * sqrt_dt;
        const float dw1 = dr1 * sqrt_dt;
        const float dw2 = dr2 * sqrt_dt;

        const float f = 0.5f * qq * qq;
        Y = Y - f * DT + (oz0 * dw0 + oz1 * dw1 + oz2 * dw2);

        const float s0 = 0.2f + 0.1f * fast_tanh(y0);
        const float s1 = 0.2f + 0.1f * fast_tanh(y1);
        const float s2 = 0.2f + 0.1f * fast_tanh(y2);
        y0 = y0 + (qq - y0) * DT + s0 * dw0;
        y1 = y1 + (qq - y1) * DT + s1 * dw1;
        y2 = y2 + (qq - y2) * DT + s2 * dw2;
    }

    // Lane-groups 2,3 are bitwise duplicates of 0,1 -- count each path once.
    const float term = y0 * y0 + y1 * y1 + y2 * y2;
    const float d    = Y - term;
    float val = (g < 2) ? d * d : 0.0f;
#pragma unroll
    for (int off = 32; off > 0; off >>= 1)
        val += __shfl_down(val, off, 64);
    if (lane == 0)
        atomicAdd(out, val * (1.0f / (float)B));
}

extern "C" void kernel_launch(void* const* d_in, const int* in_sizes, int n_in,
                              void* d_out, int out_size, void* d_ws, size_t ws_size,
                              hipStream_t stream) {
    const float* y0  = (const float*)d_in[0];
    const float* Y0  = (const float*)d_in[1];
    const float* qW1 = (const float*)d_in[2];
    const float* qb1 = (const float*)d_in[3];
    const float* qW2 = (const float*)d_in[4];
    const float* qb2 = (const float*)d_in[5];
    const float* qW3 = (const float*)d_in[6];
    const float* qb3 = (const float*)d_in[7];
    const float* zW1 = (const float*)d_in[8];
    const float* zb1 = (const float*)d_in[9];
    const float* zW2 = (const float*)d_in[10];
    const float* zb2 = (const float*)d_in[11];
    const float* zW3 = (const float*)d_in[12];
    const float* zb3 = (const float*)d_in[13];
    const float* dW  = (const float*)d_in[14];

    const int B = in_sizes[14] / (N_STEPS * 3);   // 131072
    float* out = (float*)d_out;

    hipMemsetAsync(out, 0, sizeof(float), stream);

    const int threads = 64;                        // 1 wave, both nets, 32 paths
    const int blocks  = B / 32;                    // 4096 waves -> 4/SIMD
    bsde_kernel<<<blocks, threads, 0, stream>>>(
        y0, Y0, qW1, qb1, qW2, qb2, qW3, qb3,
        zW1, zb1, zW2, zb2, zW3, zb3, dW, out, B);
}